// Round 18
// baseline (76.560 us; speedup 1.0000x reference)
//
#include <hip/hip_runtime.h>

#define NN   8192
#define DIM  128

// ---- workspace layout (bytes) ----
#define OFF_HB    0UL          // ushort Hb[8192][128] (bf16)  2,097,152
#define OFF_ASRC  2097152UL    // float asrc[8192]                32,768
#define OFF_ADST  2129920UL    // float adst[8192]                32,768
#define OFF_MASK  2162688UL    // uint mask[256][8192]         8,388,608
#define WS_NEEDED 10551296UL

#define ROW_CAP  256   // max neighbors/row (mean 82; 19-sigma headroom)

typedef unsigned short ushortx8 __attribute__((ext_vector_type(8)));

__device__ __forceinline__ unsigned short f2bf(float f) {  // RNE
    unsigned int u = __builtin_bit_cast(unsigned int, f);
    u += 0x7fffu + ((u >> 16) & 1u);
    return (unsigned short)(u >> 16);
}
__device__ __forceinline__ float bf2f(unsigned short s) {
    return __builtin_bit_cast(float, (unsigned int)s << 16);
}

// ---------------------------------------------------------------------------
// K1 — BYTE-EXACT R14 winner (71.1 µs config): 512 streams x 16 KB bursts,
// unroll 2; gemm[0,256) + alpha[256,288) + sparsify[288,800).
// ---------------------------------------------------------------------------
__global__ __launch_bounds__(256, 4) void k_phase1(
    const float* __restrict__ x, const float* __restrict__ adj,
    const float* __restrict__ w, const float* __restrict__ att_s,
    const float* __restrict__ att_d, unsigned short* __restrict__ Hb,
    float* __restrict__ asrc, float* __restrict__ adst,
    unsigned int* __restrict__ mask)
{
    __shared__ union {
        struct { float xa[64][17]; float wb[16][68]; } g;   // 8704 B
        struct { float vs[128]; float vd[128]; } a;         // 1024 B
    } sm;

    const int tid = threadIdx.x;
    const int b   = blockIdx.x;

    if (b < 256) {
        // ---------------- gemm (verified R8/R9 body) -----------------------
        const int i0g = (b >> 1) * 64;
        const int o0  = (b & 1) * 64;
        const int tx  = tid & 15;
        const int ty  = tid >> 4;
        float acc[4][4];
#pragma unroll
        for (int i = 0; i < 4; ++i)
#pragma unroll
            for (int j = 0; j < 4; ++j) acc[i][j] = 0.f;

        for (int kt = 0; kt < 8; ++kt) {
            __syncthreads();
            {
                const int r  = tid >> 2;
                const int kq = tid & 3;
                float4 v = *reinterpret_cast<const float4*>(
                    x + (size_t)(i0g + r) * DIM + kt * 16 + kq * 4);
                sm.g.xa[r][kq * 4 + 0] = v.x;
                sm.g.xa[r][kq * 4 + 1] = v.y;
                sm.g.xa[r][kq * 4 + 2] = v.z;
                sm.g.xa[r][kq * 4 + 3] = v.w;
            }
            {
                const int o  = tid & 63;
                const int kq = tid >> 6;
                float4 v = *reinterpret_cast<const float4*>(
                    w + (size_t)(o0 + o) * DIM + kt * 16 + kq * 4);
                sm.g.wb[kq * 4 + 0][o] = v.x;
                sm.g.wb[kq * 4 + 1][o] = v.y;
                sm.g.wb[kq * 4 + 2][o] = v.z;
                sm.g.wb[kq * 4 + 3][o] = v.w;
            }
            __syncthreads();
#pragma unroll
            for (int kk = 0; kk < 16; ++kk) {
                float4 wv4 = *reinterpret_cast<const float4*>(&sm.g.wb[kk][tx * 4]);
#pragma unroll
                for (int i = 0; i < 4; ++i) {
                    const float xv = sm.g.xa[ty * 4 + i][kk];
                    acc[i][0] += xv * wv4.x;
                    acc[i][1] += xv * wv4.y;
                    acc[i][2] += xv * wv4.z;
                    acc[i][3] += xv * wv4.w;
                }
            }
        }
#pragma unroll
        for (int i = 0; i < 4; ++i) {
            ushort4 h4;
            h4.x = f2bf(acc[i][0]);
            h4.y = f2bf(acc[i][1]);
            h4.z = f2bf(acc[i][2]);
            h4.w = f2bf(acc[i][3]);
            *reinterpret_cast<ushort4*>(
                Hb + (size_t)(i0g + ty * 4 + i) * DIM + o0 + tx * 4) = h4;
        }

    } else if (b < 288) {
        // ---------------- alpha (verified R8/R9 body) ----------------------
        const int t = b - 256;
        {
            const int is_d = tid >> 7;
            const int k    = tid & 127;
            const float* av = is_d ? att_d : att_s;
            float acc = 0.f;
            for (int o = 0; o < 128; ++o)
                acc += w[(size_t)o * 128 + k] * av[o];
            (is_d ? sm.a.vd : sm.a.vs)[k] = acc;
        }
        __syncthreads();
        const int r = t * 256 + tid;
        const float4* xr = reinterpret_cast<const float4*>(x + (size_t)r * DIM);
        float ss = 0.f, dd = 0.f;
#pragma unroll 8
        for (int q = 0; q < 32; ++q) {
            float4 xv = xr[q];
#pragma unroll
            for (int e = 0; e < 4; ++e) {
                const int k = q * 4 + e;
                const float xk = (&xv.x)[e];
                ss += xk * sm.a.vs[k];
                dd += xk * sm.a.vd[k];
            }
        }
        asrc[r] = ss;
        adst[r] = dd;

    } else {
        // ---------------- sparsify: 16 KB bursts, unroll 2 (R14) -----------
        const int s  = b - 288;            // 0..511
        const int g  = s >> 1;             // j-chunk
        const int q  = s & 1;              // column half
        const int ib = q * 4096 + tid * 4; // this thread's first column
        const float* rowbase = adj + (size_t)g * 32 * NN + ib;

        unsigned int m[4][4];
#pragma unroll
        for (int c = 0; c < 4; ++c)
#pragma unroll
            for (int e = 0; e < 4; ++e) m[c][e] = 0u;

#pragma unroll 2
        for (int j = 0; j < 32; ++j) {
            const float* jrow = rowbase + (size_t)j * NN;
            const unsigned int bb = 1u << j;
#pragma unroll
            for (int c = 0; c < 4; ++c) {
                float4 v = *reinterpret_cast<const float4*>(jrow + c * 1024);
                if (v.x != 0.f) m[c][0] |= bb;
                if (v.y != 0.f) m[c][1] |= bb;
                if (v.z != 0.f) m[c][2] |= bb;
                if (v.w != 0.f) m[c][3] |= bb;
            }
        }
        unsigned int* mrow = mask + (size_t)g * NN + ib;
#pragma unroll
        for (int c = 0; c < 4; ++c)
            *reinterpret_cast<uint4*>(mrow + c * 1024) =
                make_uint4(m[c][0], m[c][1], m[c][2], m[c][3]);
    }
}

// ---------------------------------------------------------------------------
// K2 gather — fused weights: the separate weight pass / wl array / butterfly
// / pad writes are gone. Each 16-lane group computes its neighbor's weight
// inline (redundant x16, broadcast asrc load, hw exp), masks the tail with
// validity predicates, and the shfl_xor(16,32) reduce yields dims AND the
// denominator together.
// ---------------------------------------------------------------------------
__global__ __launch_bounds__(256, 8) void k_gather(
    const unsigned int* __restrict__ mask, const unsigned short* __restrict__ Hb,
    const float* __restrict__ asrc, const float* __restrict__ adst,
    float* __restrict__ out)
{
    __shared__ unsigned int mt[8][256];
    __shared__ int s_jl[4][260];

    const int tid  = threadIdx.x;
    const int b    = blockIdx.x;
    const int lane = tid & 63;
    const int wv   = tid >> 6;
    const int i0 = (((b & 7) << 7) | (b >> 3)) * 8;   // XCD-chunked rows

#pragma unroll
    for (int p = 0; p < 2; ++p) {
        const int q   = p * 256 + tid;
        const int g   = q >> 1;
        const int ii4 = (q & 1) * 4;
        uint4 v = *reinterpret_cast<const uint4*>(mask + (size_t)g * NN + i0 + ii4);
        mt[ii4 + 0][g] = v.x;
        mt[ii4 + 1][g] = v.y;
        mt[ii4 + 2][g] = v.z;
        mt[ii4 + 3][g] = v.w;
    }
    __syncthreads();

    int* const jl = s_jl[wv];

    for (int rr = 0; rr < 2; ++rr) {
        const int ii = wv * 2 + rr;
        const int i  = i0 + ii;

        uint4 mv = *reinterpret_cast<const uint4*>(&mt[ii][4 * lane]);
        const int csum = __popc(mv.x) + __popc(mv.y) + __popc(mv.z) + __popc(mv.w);

        int incl = csum;
#pragma unroll
        for (int off = 1; off < 64; off <<= 1) {
            int tt = __shfl_up(incl, off);
            if (lane >= off) incl += tt;
        }
        const int cnt = min(__shfl(incl, 63), ROW_CAP);
        int off = incl - csum;

#define EXTRACT(mm, q)                                                  \
        {                                                               \
            unsigned int z = (mm);                                      \
            const int jb = (4 * lane + (q)) * 32;                       \
            while (z) {                                                 \
                const int bb = __builtin_ctz(z);                        \
                z &= z - 1;                                             \
                if (off < ROW_CAP) jl[off] = jb + bb;                   \
                ++off;                                                  \
            }                                                           \
        }
        EXTRACT(mv.x, 0) EXTRACT(mv.y, 1) EXTRACT(mv.z, 2) EXTRACT(mv.w, 3)
#undef EXTRACT
        __builtin_amdgcn_wave_barrier();

        // fused gather + weights: group grp owns neighbor k+grp
        const float adst_i = adst[i];
        const int grp = lane >> 4;
        const int l16 = lane & 15;
        const int cnt4 = (cnt + 3) & ~3;
        float a0 = 0.f, a1 = 0.f, a2 = 0.f, a3 = 0.f;
        float a4 = 0.f, a5 = 0.f, a6 = 0.f, a7 = 0.f;
        float wsum = 0.f;
        for (int k = 0; k < cnt4; k += 4) {
            const int  idx   = k + grp;
            const bool valid = idx < cnt;
            const int  j     = valid ? jl[idx] : 0;       // clamped: safe addr
            const float cv   = asrc[j] + adst_i;          // broadcast load
            const float ww   = valid ? __expf(fmaxf(0.2f * cv, cv)) : 0.f;
            ushortx8 h = *reinterpret_cast<const ushortx8*>(
                Hb + (size_t)j * DIM + l16 * 8);
            a0 += ww * bf2f(h.s0);
            a1 += ww * bf2f(h.s1);
            a2 += ww * bf2f(h.s2);
            a3 += ww * bf2f(h.s3);
            a4 += ww * bf2f(h.s4);
            a5 += ww * bf2f(h.s5);
            a6 += ww * bf2f(h.s6);
            a7 += ww * bf2f(h.s7);
            wsum += ww;
        }
        // cross-group reduce: dims AND denominator together
#pragma unroll
        for (int m = 16; m <= 32; m <<= 1) {
            a0 += __shfl_xor(a0, m);
            a1 += __shfl_xor(a1, m);
            a2 += __shfl_xor(a2, m);
            a3 += __shfl_xor(a3, m);
            a4 += __shfl_xor(a4, m);
            a5 += __shfl_xor(a5, m);
            a6 += __shfl_xor(a6, m);
            a7 += __shfl_xor(a7, m);
            wsum += __shfl_xor(wsum, m);
        }
        const float inv = 1.f / wsum;   // self-loops guarantee > 0
        if (grp == 0) {
            float* op = out + (size_t)i * DIM + l16 * 8;
            *reinterpret_cast<float4*>(op)     = make_float4(a0*inv, a1*inv, a2*inv, a3*inv);
            *reinterpret_cast<float4*>(op + 4) = make_float4(a4*inv, a5*inv, a6*inv, a7*inv);
        }
    }
}

extern "C" void kernel_launch(void* const* d_in, const int* in_sizes, int n_in,
                              void* d_out, int out_size, void* d_ws, size_t ws_size,
                              hipStream_t stream)
{
    const float* x     = (const float*)d_in[0];
    const float* adj   = (const float*)d_in[1];
    const float* w     = (const float*)d_in[2];
    const float* att_s = (const float*)d_in[3];
    const float* att_d = (const float*)d_in[4];
    float* out = (float*)d_out;

    if (ws_size < WS_NEEDED) return;  // loud failure (output stays poisoned)

    char* ws = (char*)d_ws;
    unsigned short* Hb   = (unsigned short*)(ws + OFF_HB);
    float*          asrc = (float*)(ws + OFF_ASRC);
    float*          adst = (float*)(ws + OFF_ADST);
    unsigned int*   mask = (unsigned int*)(ws + OFF_MASK);

    k_phase1<<<800,  256, 0, stream>>>(x, adj, w, att_s, att_d, Hb, asrc, adst, mask);
    k_gather<<<1024, 256, 0, stream>>>(mask, Hb, asrc, adst, out);
}

// Round 19
// 70.661 us; speedup vs baseline: 1.0835x; 1.0835x over previous
//
#include <hip/hip_runtime.h>

#define NN   8192
#define DIM  128

// ---- workspace layout (bytes) ----
#define OFF_HB    0UL          // ushort Hb[8192][128] (bf16)  2,097,152
#define OFF_ASRC  2097152UL    // float asrc[8192]                32,768
#define OFF_ADST  2129920UL    // float adst[8192]                32,768
#define OFF_MASK  2162688UL    // uint mask[256][8192]         8,388,608
#define WS_NEEDED 10551296UL

#define ROW_CAP  256   // max neighbors/row (mean 82; 19-sigma headroom)

typedef unsigned short ushortx8 __attribute__((ext_vector_type(8)));

__device__ __forceinline__ unsigned short f2bf(float f) {  // RNE
    unsigned int u = __builtin_bit_cast(unsigned int, f);
    u += 0x7fffu + ((u >> 16) & 1u);
    return (unsigned short)(u >> 16);
}
__device__ __forceinline__ float bf2f(unsigned short s) {
    return __builtin_bit_cast(float, (unsigned int)s << 16);
}

// ---------------------------------------------------------------------------
// K1 — R14 champion (71.1 µs): 512 streams x 16 KB bursts, unroll 2.
//   [0, 256)   gemm: Hb = bf16(x W^T), 64x64 tiles
//   [256, 288) alpha: asrc = x (W^T att_s), adst = x (W^T att_d)
//   [288, 800) sparsify: block (g, q) = j-chunk g, column half q;
//              32 rows x 16 KB contiguous bursts; contiguous mask stores.
// ---------------------------------------------------------------------------
__global__ __launch_bounds__(256, 4) void k_phase1(
    const float* __restrict__ x, const float* __restrict__ adj,
    const float* __restrict__ w, const float* __restrict__ att_s,
    const float* __restrict__ att_d, unsigned short* __restrict__ Hb,
    float* __restrict__ asrc, float* __restrict__ adst,
    unsigned int* __restrict__ mask)
{
    __shared__ union {
        struct { float xa[64][17]; float wb[16][68]; } g;   // 8704 B
        struct { float vs[128]; float vd[128]; } a;         // 1024 B
    } sm;

    const int tid = threadIdx.x;
    const int b   = blockIdx.x;

    if (b < 256) {
        // ---------------- gemm (verified R8/R9 body) -----------------------
        const int i0g = (b >> 1) * 64;
        const int o0  = (b & 1) * 64;
        const int tx  = tid & 15;
        const int ty  = tid >> 4;
        float acc[4][4];
#pragma unroll
        for (int i = 0; i < 4; ++i)
#pragma unroll
            for (int j = 0; j < 4; ++j) acc[i][j] = 0.f;

        for (int kt = 0; kt < 8; ++kt) {
            __syncthreads();
            {
                const int r  = tid >> 2;
                const int kq = tid & 3;
                float4 v = *reinterpret_cast<const float4*>(
                    x + (size_t)(i0g + r) * DIM + kt * 16 + kq * 4);
                sm.g.xa[r][kq * 4 + 0] = v.x;
                sm.g.xa[r][kq * 4 + 1] = v.y;
                sm.g.xa[r][kq * 4 + 2] = v.z;
                sm.g.xa[r][kq * 4 + 3] = v.w;
            }
            {
                const int o  = tid & 63;
                const int kq = tid >> 6;
                float4 v = *reinterpret_cast<const float4*>(
                    w + (size_t)(o0 + o) * DIM + kt * 16 + kq * 4);
                sm.g.wb[kq * 4 + 0][o] = v.x;
                sm.g.wb[kq * 4 + 1][o] = v.y;
                sm.g.wb[kq * 4 + 2][o] = v.z;
                sm.g.wb[kq * 4 + 3][o] = v.w;
            }
            __syncthreads();
#pragma unroll
            for (int kk = 0; kk < 16; ++kk) {
                float4 wv4 = *reinterpret_cast<const float4*>(&sm.g.wb[kk][tx * 4]);
#pragma unroll
                for (int i = 0; i < 4; ++i) {
                    const float xv = sm.g.xa[ty * 4 + i][kk];
                    acc[i][0] += xv * wv4.x;
                    acc[i][1] += xv * wv4.y;
                    acc[i][2] += xv * wv4.z;
                    acc[i][3] += xv * wv4.w;
                }
            }
        }
#pragma unroll
        for (int i = 0; i < 4; ++i) {
            ushort4 h4;
            h4.x = f2bf(acc[i][0]);
            h4.y = f2bf(acc[i][1]);
            h4.z = f2bf(acc[i][2]);
            h4.w = f2bf(acc[i][3]);
            *reinterpret_cast<ushort4*>(
                Hb + (size_t)(i0g + ty * 4 + i) * DIM + o0 + tx * 4) = h4;
        }

    } else if (b < 288) {
        // ---------------- alpha (verified R8/R9 body) ----------------------
        const int t = b - 256;
        {
            const int is_d = tid >> 7;
            const int k    = tid & 127;
            const float* av = is_d ? att_d : att_s;
            float acc = 0.f;
            for (int o = 0; o < 128; ++o)
                acc += w[(size_t)o * 128 + k] * av[o];
            (is_d ? sm.a.vd : sm.a.vs)[k] = acc;
        }
        __syncthreads();
        const int r = t * 256 + tid;
        const float4* xr = reinterpret_cast<const float4*>(x + (size_t)r * DIM);
        float ss = 0.f, dd = 0.f;
#pragma unroll 8
        for (int q = 0; q < 32; ++q) {
            float4 xv = xr[q];
#pragma unroll
            for (int e = 0; e < 4; ++e) {
                const int k = q * 4 + e;
                const float xk = (&xv.x)[e];
                ss += xk * sm.a.vs[k];
                dd += xk * sm.a.vd[k];
            }
        }
        asrc[r] = ss;
        adst[r] = dd;

    } else {
        // ---------------- sparsify: 16 KB bursts, unroll 2 -----------------
        const int s  = b - 288;            // 0..511
        const int g  = s >> 1;             // j-chunk
        const int q  = s & 1;              // column half
        const int ib = q * 4096 + tid * 4; // this thread's first column
        const float* rowbase = adj + (size_t)g * 32 * NN + ib;

        unsigned int m[4][4];
#pragma unroll
        for (int c = 0; c < 4; ++c)
#pragma unroll
            for (int e = 0; e < 4; ++e) m[c][e] = 0u;

#pragma unroll 2
        for (int j = 0; j < 32; ++j) {
            const float* jrow = rowbase + (size_t)j * NN;
            const unsigned int bb = 1u << j;
#pragma unroll
            for (int c = 0; c < 4; ++c) {
                float4 v = *reinterpret_cast<const float4*>(jrow + c * 1024);
                if (v.x != 0.f) m[c][0] |= bb;
                if (v.y != 0.f) m[c][1] |= bb;
                if (v.z != 0.f) m[c][2] |= bb;
                if (v.w != 0.f) m[c][3] |= bb;
            }
        }
        unsigned int* mrow = mask + (size_t)g * NN + ib;
#pragma unroll
        for (int c = 0; c < 4; ++c)
            *reinterpret_cast<uint4*>(mrow + c * 1024) =
                make_uint4(m[c][0], m[c][1], m[c][2], m[c][3]);
    }
}

// ---------------------------------------------------------------------------
// K2 gather — R14 champion body (two-pass weights, 4-neighbor float4 gather).
// ---------------------------------------------------------------------------
__global__ __launch_bounds__(256, 8) void k_gather(
    const unsigned int* __restrict__ mask, const unsigned short* __restrict__ Hb,
    const float* __restrict__ asrc, const float* __restrict__ adst,
    float* __restrict__ out)
{
    __shared__ unsigned int mt[8][256];
    __shared__ int   s_jl[4][260];
    __shared__ float s_wl[4][260];

    const int tid  = threadIdx.x;
    const int b    = blockIdx.x;
    const int lane = tid & 63;
    const int wv   = tid >> 6;
    const int i0 = (((b & 7) << 7) | (b >> 3)) * 8;   // XCD-chunked rows

#pragma unroll
    for (int p = 0; p < 2; ++p) {
        const int q   = p * 256 + tid;
        const int g   = q >> 1;
        const int ii4 = (q & 1) * 4;
        uint4 v = *reinterpret_cast<const uint4*>(mask + (size_t)g * NN + i0 + ii4);
        mt[ii4 + 0][g] = v.x;
        mt[ii4 + 1][g] = v.y;
        mt[ii4 + 2][g] = v.z;
        mt[ii4 + 3][g] = v.w;
    }
    __syncthreads();

    int* const   jl = s_jl[wv];
    float* const wl = s_wl[wv];

    for (int rr = 0; rr < 2; ++rr) {
        const int ii = wv * 2 + rr;
        const int i  = i0 + ii;

        uint4 mv = *reinterpret_cast<const uint4*>(&mt[ii][4 * lane]);
        const int csum = __popc(mv.x) + __popc(mv.y) + __popc(mv.z) + __popc(mv.w);

        int incl = csum;
#pragma unroll
        for (int off = 1; off < 64; off <<= 1) {
            int tt = __shfl_up(incl, off);
            if (lane >= off) incl += tt;
        }
        const int cnt = min(__shfl(incl, 63), ROW_CAP);
        int off = incl - csum;

#define EXTRACT(mm, q)                                                  \
        {                                                               \
            unsigned int z = (mm);                                      \
            const int jb = (4 * lane + (q)) * 32;                       \
            while (z) {                                                 \
                const int bb = __builtin_ctz(z);                        \
                z &= z - 1;                                             \
                if (off < ROW_CAP) jl[off] = jb + bb;                   \
                ++off;                                                  \
            }                                                           \
        }
        EXTRACT(mv.x, 0) EXTRACT(mv.y, 1) EXTRACT(mv.z, 2) EXTRACT(mv.w, 3)
#undef EXTRACT
        __builtin_amdgcn_wave_barrier();

        const float adst_i = adst[i];
        float dsum = 0.f;
        for (int t = lane; t < cnt; t += 64) {
            const float cv = asrc[jl[t]] + adst_i;
            const float wgt = __expf(fmaxf(0.2f * cv, cv));
            wl[t] = wgt;
            dsum += wgt;
        }
#pragma unroll
        for (int mo = 1; mo < 64; mo <<= 1) dsum += __shfl_xor(dsum, mo);
        const float inv = 1.f / dsum;       // self-loops guarantee > 0

        if (lane == 0) {
            const int cnt4l = (cnt + 3) & ~3;
            for (int e = cnt; e < cnt4l; ++e) { jl[e] = i; wl[e] = 0.f; }
        }
        __builtin_amdgcn_wave_barrier();
        const int cnt4 = (cnt + 3) & ~3;

        const int grp = lane >> 4;
        const int l16 = lane & 15;
        float a0 = 0.f, a1 = 0.f, a2 = 0.f, a3 = 0.f;
        float a4 = 0.f, a5 = 0.f, a6 = 0.f, a7 = 0.f;
        for (int k = 0; k < cnt4; k += 4) {
            const int   j  = jl[k + grp];
            const float ww = wl[k + grp];
            ushortx8 h = *reinterpret_cast<const ushortx8*>(
                Hb + (size_t)j * DIM + l16 * 8);
            a0 += ww * bf2f(h.s0);
            a1 += ww * bf2f(h.s1);
            a2 += ww * bf2f(h.s2);
            a3 += ww * bf2f(h.s3);
            a4 += ww * bf2f(h.s4);
            a5 += ww * bf2f(h.s5);
            a6 += ww * bf2f(h.s6);
            a7 += ww * bf2f(h.s7);
        }
#pragma unroll
        for (int m = 16; m <= 32; m <<= 1) {
            a0 += __shfl_xor(a0, m);
            a1 += __shfl_xor(a1, m);
            a2 += __shfl_xor(a2, m);
            a3 += __shfl_xor(a3, m);
            a4 += __shfl_xor(a4, m);
            a5 += __shfl_xor(a5, m);
            a6 += __shfl_xor(a6, m);
            a7 += __shfl_xor(a7, m);
        }
        if (grp == 0) {
            float* op = out + (size_t)i * DIM + l16 * 8;
            *reinterpret_cast<float4*>(op)     = make_float4(a0*inv, a1*inv, a2*inv, a3*inv);
            *reinterpret_cast<float4*>(op + 4) = make_float4(a4*inv, a5*inv, a6*inv, a7*inv);
        }
    }
}

extern "C" void kernel_launch(void* const* d_in, const int* in_sizes, int n_in,
                              void* d_out, int out_size, void* d_ws, size_t ws_size,
                              hipStream_t stream)
{
    const float* x     = (const float*)d_in[0];
    const float* adj   = (const float*)d_in[1];
    const float* w     = (const float*)d_in[2];
    const float* att_s = (const float*)d_in[3];
    const float* att_d = (const float*)d_in[4];
    float* out = (float*)d_out;

    if (ws_size < WS_NEEDED) return;  // loud failure (output stays poisoned)

    char* ws = (char*)d_ws;
    unsigned short* Hb   = (unsigned short*)(ws + OFF_HB);
    float*          asrc = (float*)(ws + OFF_ASRC);
    float*          adst = (float*)(ws + OFF_ADST);
    unsigned int*   mask = (unsigned int*)(ws + OFF_MASK);

    k_phase1<<<800,  256, 0, stream>>>(x, adj, w, att_s, att_d, Hb, asrc, adst, mask);
    k_gather<<<1024, 256, 0, stream>>>(mask, Hb, asrc, adst, out);
}